// Round 5
// baseline (1248.792 us; speedup 1.0000x reference)
//
#include <hip/hip_runtime.h>

typedef unsigned short u16;
typedef __attribute__((ext_vector_type(8))) short bs8;
typedef __attribute__((ext_vector_type(4))) float fx4;
#define MFMA16(a,b,c) __builtin_amdgcn_mfma_f32_16x16x32_bf16(a,b,c,0,0,0)

__device__ __forceinline__ float b2f(u16 u){ return __uint_as_float(((unsigned int)u) << 16); }
__device__ __forceinline__ u16 f2b(float f){
  unsigned int x = __float_as_uint(f);
  unsigned int r = (x + 0x7FFFu + ((x >> 16) & 1u)) >> 16;
  return (u16)r;
}
__device__ __forceinline__ float sigm(float x){ return 1.f/(1.f+__expf(-x)); }
__device__ __forceinline__ float siluf(float x){ return x/(1.f+__expf(-x)); }
__device__ __forceinline__ float wsum(float v){
  #pragma unroll
  for (int o=1;o<64;o<<=1) v += __shfl_xor(v, o);
  return v;
}
__device__ __forceinline__ float wmax(float v){
  #pragma unroll
  for (int o=1;o<64;o<<=1) v = fmaxf(v, __shfl_xor(v, o));
  return v;
}
__device__ __forceinline__ bs8 lds8(const u16* ptr){ return *reinterpret_cast<const bs8*>(ptr); }
__device__ __forceinline__ bs8 glb8(const u16* ptr){ return *reinterpret_cast<const bs8*>(ptr); }

// LDS strides (elements, all multiples of 8 for 16B-aligned b128 reads)
#define XSB_P 328   // [nodes][328] bf16 : cols 0..255 xs, 256..319 vn
#define XVB_P 72    // [3*nodes][72] bf16 : row = c*NODES+node
#define SGB_P 264   // [nodes][264] bf16
#define UBUF_P 68   // [nodes][68]  f32
#define XQ_P 456    // [16][456] bf16 (k3)
#define AT_P 72     // [16][72]  bf16 (k3)

struct GP {
  const float* x_s; const float* x_v; const int* bidx;
  const float* wh[5]; const float* ws_w[5]; const float* ws_b[5];
  const float* wv[4]; const float* wsv_w[4]; const float* wsv_b[4];
  const float *w1, *b1, *lng, *lnb, *w2, *b2, *gbias;
  u16 *wsP, *whP, *wvP, *wsvP, *w1P, *w2P;   // MFMA-B-fragment packed bf16
  float *wsb_f, *wsvb_f, *b1_f, *b2_f, *lng_f, *lnb_f, *gb_f;
  u16 *Ks, *Vs, *Kv, *Vv, *Gs;
  u16 *Pmb;
  float *Gv, *CK, *CV;
  u16 *CKP, *CVP;                            // packed bf16 B-frags for attention
  float *Qs, *Qv;   // live inside d_out (f32 scratch, overwritten with final output)
};

// ---------- prep: pack weights into MFMA B-fragment order, biases f32 --------
// B-frag: element (kstep,ntile,lane,j) = W_orig[n = ntile*16+(lane&15)][k = kstep*32+(lane>>4)*8+j]
__global__ __launch_bounds__(256) void kprep(GP p){
  int idx = blockIdx.x*256 + threadIdx.x;
  if (idx < 409600){            // wsP: 5 sets, K=320 (10 ks), N=256 (16 nt)
    int s=idx/81920, r=idx%81920;
    int ks=r/8192, r2=r%8192, nt=r2/512, r3=r2%512, ln=r3/8, j=r3%8;
    int n=nt*16+(ln&15), k=ks*32+((ln>>4)*8)+j;
    p.wsP[idx] = f2b(p.ws_w[s][n*320+k]); return;
  }
  idx -= 409600;
  if (idx < 20480){             // whP: 5 sets, K=64 (2 ks), N=64 (4 nt)
    int s=idx/4096, r=idx%4096;
    int ks=r/2048, r2=r%2048, nt=r2/512, r3=r2%512, ln=r3/8, j=r3%8;
    int h=nt*16+(ln&15), d=ks*32+((ln>>4)*8)+j;
    p.whP[idx] = f2b(p.wh[s][h*64+d]); return;
  }
  idx -= 20480;
  if (idx < 16384){             // wvP: 4 sets, K=64, N=64
    int s=idx/4096, r=idx%4096;
    int ks=r/2048, r2=r%2048, nt=r2/512, r3=r2%512, ln=r3/8, j=r3%8;
    int dd=nt*16+(ln&15), hh=ks*32+((ln>>4)*8)+j;
    p.wvP[idx] = f2b(p.wv[s][dd*64+hh]); return;
  }
  idx -= 16384;
  if (idx < 65536){             // wsvP: 4 sets, K=256 (8 ks), N=64 (4 nt)
    int s=idx/16384, r=idx%16384;
    int ks=r/2048, r2=r%2048, nt=r2/512, r3=r2%512, ln=r3/8, j=r3%8;
    int dd=nt*16+(ln&15), i=ks*32+((ln>>4)*8)+j;
    p.wsvP[idx] = f2b(p.wsv_w[s][dd*256+i]); return;
  }
  idx -= 65536;
  if (idx < 65536){             // w1P: K=256 (8 ks), N=256 (16 nt)
    int ks=idx/8192, r2=idx%8192, nt=r2/512, r3=r2%512, ln=r3/8, j=r3%8;
    int n=nt*16+(ln&15), k=ks*32+((ln>>4)*8)+j;
    p.w1P[idx] = f2b(p.w1[n*256+k]); return;
  }
  idx -= 65536;
  if (idx < 16384){             // w2P: K=256 (8 ks), N=64 (4 nt)
    int ks=idx/2048, r2=idx%2048, nt=r2/512, r3=r2%512, ln=r3/8, j=r3%8;
    int rr=nt*16+(ln&15), i=ks*32+((ln>>4)*8)+j;
    p.w2P[idx] = f2b(p.w2[rr*256+i]); return;
  }
  idx -= 16384;
  if (idx < 1280){ int s=idx>>8, i=idx&255; p.wsb_f[idx] = p.ws_b[s][i]; return; }
  idx -= 1280;
  if (idx < 256){ int s=idx>>6, d=idx&63; p.wsvb_f[idx] = p.wsv_b[s][d]; return; }
  idx -= 256;
  if (idx < 256){ p.b1_f[idx] = p.b1[idx]; return; }
  idx -= 256;
  if (idx < 64){ p.b2_f[idx] = p.b2[idx]; return; }
  idx -= 64;
  if (idx < 256){ p.lng_f[idx] = p.lng[idx]; return; }
  idx -= 256;
  if (idx < 256){ p.lnb_f[idx] = p.lnb[idx]; return; }
  idx -= 256;
  if (idx < 256){ p.gb_f[idx] = p.gbias[idx]; return; }
}

// =============== 32-node MFMA building blocks (k1) ==========================
__device__ __forceinline__ void mfma_vh_vn32(const u16* whPs, const u16* xvb, u16* vhb2,
                                             u16* xsb, int lane, int wave, int tid){
  fx4 a[2][3];
  #pragma unroll
  for (int mt=0;mt<2;mt++)
    #pragma unroll
    for (int c=0;c<3;c++) a[mt][c]=(fx4){0.f,0.f,0.f,0.f};
  #pragma unroll
  for (int ks=0; ks<2; ks++){
    bs8 b = glb8(whPs + (ks*4+wave)*512 + lane*8);
    #pragma unroll
    for (int mt=0;mt<2;mt++)
      #pragma unroll
      for (int c=0;c<3;c++){
        bs8 x = lds8(xvb + (c*32 + mt*16 + (lane&15))*XVB_P + ks*32 + ((lane>>4)*8));
        a[mt][c] = MFMA16(x,b,a[mt][c]);
      }
  }
  int h = wave*16 + (lane&15);
  int mrow = (lane>>4)*4;
  #pragma unroll
  for (int mt=0;mt<2;mt++)
    #pragma unroll
    for (int c=0;c<3;c++)
      #pragma unroll
      for (int r=0;r<4;r++)
        vhb2[(c*32 + mt*16 + mrow + r)*XVB_P + h] = f2b(a[mt][c][r]);
  __syncthreads();
  for (int i=tid; i<2048; i+=256){
    int node=i>>6, hh=i&63;
    float aa=b2f(vhb2[node*XVB_P+hh]);
    float bb=b2f(vhb2[(32+node)*XVB_P+hh]);
    float cc=b2f(vhb2[(64+node)*XVB_P+hh]);
    xsb[node*XSB_P + 256 + hh] = f2b(sqrtf(fmaxf(aa*aa+bb*bb+cc*cc, 1e-8f)));
  }
  __syncthreads();
}

template<int KS>
__device__ __forceinline__ void mfma_sgemm32(const u16* wsPs, const float* bias,
                                             const u16* xsb, int lane, int wave, fx4 acc[2][4]){
  #pragma unroll
  for (int mt=0;mt<2;mt++)
    #pragma unroll
    for (int t=0;t<4;t++) acc[mt][t] = (fx4){0.f,0.f,0.f,0.f};
  const u16* ar0 = xsb + (lane&15)*XSB_P + ((lane>>4)*8);
  const u16* ar1 = ar0 + 16*XSB_P;
  #pragma unroll
  for (int ks=0; ks<KS; ks++){
    bs8 a0 = lds8(ar0 + ks*32);
    bs8 a1 = lds8(ar1 + ks*32);
    #pragma unroll
    for (int t=0;t<4;t++){
      bs8 b = glb8(wsPs + (ks*16 + wave*4 + t)*512 + lane*8);
      acc[0][t] = MFMA16(a0,b,acc[0][t]);
      acc[1][t] = MFMA16(a1,b,acc[1][t]);
    }
  }
  #pragma unroll
  for (int t=0;t<4;t++){
    float bv = bias[(wave*4+t)*16 + (lane&15)];
    #pragma unroll
    for (int mt=0;mt<2;mt++){
      acc[mt][t][0]+=bv; acc[mt][t][1]+=bv; acc[mt][t][2]+=bv; acc[mt][t][3]+=bv;
    }
  }
}

__device__ __forceinline__ void mfma_g64_32(const u16* bP, const u16* sgb,
                                            int lane, int wave, fx4 g[2]){
  g[0]=(fx4){0.f,0.f,0.f,0.f}; g[1]=g[0];
  const u16* ar0 = sgb + (lane&15)*SGB_P + ((lane>>4)*8);
  const u16* ar1 = ar0 + 16*SGB_P;
  #pragma unroll
  for (int ks=0; ks<8; ks++){
    bs8 b = glb8(bP + (ks*4 + wave)*512 + lane*8);
    g[0] = MFMA16(lds8(ar0 + ks*32), b, g[0]);
    g[1] = MFMA16(lds8(ar1 + ks*32), b, g[1]);
  }
}

__device__ __forceinline__ void mfma_wv32(const u16* wvPs, const u16* vhb2,
                                          int lane, int wave, fx4 vo[2][3]){
  #pragma unroll
  for (int mt=0;mt<2;mt++)
    #pragma unroll
    for (int c=0;c<3;c++) vo[mt][c]=(fx4){0.f,0.f,0.f,0.f};
  #pragma unroll
  for (int ks=0; ks<2; ks++){
    bs8 b = glb8(wvPs + (ks*4+wave)*512 + lane*8);
    #pragma unroll
    for (int mt=0;mt<2;mt++)
      #pragma unroll
      for (int c=0;c<3;c++){
        bs8 a = lds8(vhb2 + (c*32 + mt*16 + (lane&15))*XVB_P + ks*32 + ((lane>>4)*8));
        vo[mt][c] = MFMA16(a,b,vo[mt][c]);
      }
  }
}

// ---------------- k1: q/k/v/g GVPs + comp path (32 nodes / block) -----------
__global__ __launch_bounds__(256) void k1(GP p){
  __shared__ __align__(16) char sm1[65536];
  u16* xsb  = (u16*)sm1;                 // 32*328*2 = 20992
  u16* xvb  = (u16*)(sm1+20992);         // 96*72*2  = 13824
  u16* vhb2 = (u16*)(sm1+34816);         // 13824
  u16* sgb  = (u16*)(sm1+48640);         // 32*264*2 = 16896 (end 65536)
  float* red = (float*)vhb2;             // aliases vhb2 when dead (gate/comp)
  float* lnp = red + 256;
  float* ubuf = (float*)sgb;             // aliases sgb after its last read

  const int tid = threadIdx.x, lane = tid&63, wave = tid>>6;
  const int n0 = blockIdx.x * 32;

  for (int i=tid;i<2048;i+=256){
    int node=i>>6, c4=(i&63)*4;
    float4 v = *reinterpret_cast<const float4*>(p.x_s + (size_t)(n0+node)*256 + c4);
    u16* d = xsb + node*XSB_P + c4;
    d[0]=f2b(v.x); d[1]=f2b(v.y); d[2]=f2b(v.z); d[3]=f2b(v.w);
  }
  for (int i=tid;i<6144;i+=256){
    int row=i>>6, d=i&63, c=row>>5, node=row&31;
    xvb[row*XVB_P+d] = f2b(p.x_v[(size_t)(n0+node)*192 + d*3 + c]);
  }
  __syncthreads();

  fx4 acc[2][4];
  #pragma unroll 1
  for (int s=0; s<3; ++s){      // 0=q 1=k 2=v
    mfma_vh_vn32(p.whP + s*4096, xvb, vhb2, xsb, lane, wave, tid);
    mfma_sgemm32<10>(p.wsP + (size_t)s*81920, p.wsb_f + s*256, xsb, lane, wave, acc);
    u16* KVs = (s==1) ? p.Ks : p.Vs;
    #pragma unroll
    for (int t=0;t<4;t++){
      int ncol=(wave*4+t)*16+(lane&15);
      #pragma unroll
      for (int mt=0;mt<2;mt++)
        #pragma unroll
        for (int r=0;r<4;r++){
          int node=mt*16+((lane>>4)*4)+r;
          float v=acc[mt][t][r];
          float sl=siluf(v);
          if (s==0) p.Qs[(size_t)(n0+node)*256+ncol]=sl;
          else      KVs[(size_t)(n0+node)*256+ncol]=f2b(sl);
          sgb[node*SGB_P+ncol]=f2b(sigm(v));
        }
    }
    __syncthreads();
    fx4 g[2];
    mfma_g64_32(p.wsvP + s*16384, sgb, lane, wave, g);
    fx4 vo[2][3];
    mfma_wv32(p.wvP + s*4096, vhb2, lane, wave, vo);
    int dout = wave*16+(lane&15);
    #pragma unroll
    for (int mt=0;mt<2;mt++)
      #pragma unroll
      for (int r=0;r<4;r++){
        int node=mt*16+((lane>>4)*4)+r;
        float gg = sigm(g[mt][r] + p.wsvb_f[s*64+dout]);
        if (s==0){
          #pragma unroll
          for (int c=0;c<3;c++)
            p.Qv[(size_t)(n0+node)*192 + c*64 + dout] = vo[mt][c][r]*gg;
        } else {
          u16* KVv=(s==1)?p.Kv:p.Vv;
          #pragma unroll
          for (int c=0;c<3;c++)
            KVv[(size_t)(n0+node)*192 + c*64 + dout] = f2b(vo[mt][c][r]*gg);
        }
      }
    __syncthreads();
  }

  // gate set (vhb2 dead after helper -> red aliasing OK)
  mfma_vh_vn32(p.whP + 3*4096, xvb, vhb2, xsb, lane, wave, tid);
  mfma_sgemm32<10>(p.wsP + (size_t)3*81920, p.wsb_f + 3*256, xsb, lane, wave, acc);
  {
    float psum[2][4] = {{0.f,0.f,0.f,0.f},{0.f,0.f,0.f,0.f}};
    #pragma unroll
    for (int t=0;t<4;t++){
      int ncol=(wave*4+t)*16+(lane&15);
      float gb = p.gb_f[ncol];
      #pragma unroll
      for (int mt=0;mt<2;mt++)
        #pragma unroll
        for (int r=0;r<4;r++){
          int node=mt*16+((lane>>4)*4)+r;
          float gs = sigm(acc[mt][t][r] + gb);
          p.Gs[(size_t)(n0+node)*256+ncol] = f2b(gs);
          psum[mt][r] += gs;
        }
    }
    #pragma unroll
    for (int mt=0;mt<2;mt++)
      #pragma unroll
      for (int r=0;r<4;r++){
        #pragma unroll
        for (int o=1;o<16;o<<=1) psum[mt][r] += __shfl_xor(psum[mt][r], o);
      }
    if ((lane&15)==0){
      #pragma unroll
      for (int mt=0;mt<2;mt++)
        #pragma unroll
        for (int r=0;r<4;r++)
          red[wave*32 + mt*16+((lane>>4)*4)+r] = psum[mt][r];
    }
    __syncthreads();
    if (tid<32)
      p.Gv[n0+tid] = sigm((red[tid]+red[32+tid]+red[64+tid]+red[96+tid])*(1.f/256.f));
    __syncthreads();
  }

  // comp path: h = LN(xs @ w1^T + b1); P = softmax(silu(h) @ w2^T + b2)
  mfma_sgemm32<8>(p.w1P, p.b1_f, xsb, lane, wave, acc);
  {
    float s1[2][4]={{0.f,0.f,0.f,0.f},{0.f,0.f,0.f,0.f}};
    float s2[2][4]={{0.f,0.f,0.f,0.f},{0.f,0.f,0.f,0.f}};
    #pragma unroll
    for (int t=0;t<4;t++)
      #pragma unroll
      for (int mt=0;mt<2;mt++)
        #pragma unroll
        for (int r=0;r<4;r++){ float v=acc[mt][t][r]; s1[mt][r]+=v; s2[mt][r]+=v*v; }
    #pragma unroll
    for (int mt=0;mt<2;mt++)
      #pragma unroll
      for (int r=0;r<4;r++){
        #pragma unroll
        for (int o=1;o<16;o<<=1){
          s1[mt][r]+=__shfl_xor(s1[mt][r],o);
          s2[mt][r]+=__shfl_xor(s2[mt][r],o);
        }
      }
    if ((lane&15)==0){
      #pragma unroll
      for (int mt=0;mt<2;mt++)
        #pragma unroll
        for (int r=0;r<4;r++){
          int node=mt*16+((lane>>4)*4)+r;
          red[wave*32+node]=s1[mt][r];
          red[128+wave*32+node]=s2[mt][r];
        }
    }
    __syncthreads();
    if (tid<32){
      float S1=red[tid]+red[32+tid]+red[64+tid]+red[96+tid];
      float S2=red[128+tid]+red[160+tid]+red[192+tid]+red[224+tid];
      float mu=S1*(1.f/256.f), var=S2*(1.f/256.f)-mu*mu;
      lnp[tid]=mu; lnp[32+tid]=rsqrtf(var+1e-5f);
    }
    __syncthreads();
    #pragma unroll
    for (int t=0;t<4;t++){
      int ncol=(wave*4+t)*16+(lane&15);
      float g=p.lng_f[ncol], b=p.lnb_f[ncol];
      #pragma unroll
      for (int mt=0;mt<2;mt++)
        #pragma unroll
        for (int r=0;r<4;r++){
          int node=mt*16+((lane>>4)*4)+r;
          float h=(acc[mt][t][r]-lnp[node])*lnp[32+node]*g + b;
          sgb[node*SGB_P+ncol]=f2b(siluf(h));
        }
    }
    __syncthreads();
    fx4 u2[2];
    mfma_g64_32(p.w2P, sgb, lane, wave, u2);
    __syncthreads();           // sgb last read done; ubuf aliases sgb
    int rcol = wave*16+(lane&15);
    float b2v = p.b2_f[rcol];
    #pragma unroll
    for (int mt=0;mt<2;mt++)
      #pragma unroll
      for (int r=0;r<4;r++){
        int node=mt*16+((lane>>4)*4)+r;
        ubuf[node*UBUF_P + rcol] = u2[mt][r] + b2v;
      }
    __syncthreads();
    #pragma unroll
    for (int i=0;i<8;i++){
      int node = wave*8+i;
      float uu = ubuf[node*UBUF_P + lane];
      float m = wmax(uu);
      float e = __expf(uu-m);
      float ss = wsum(e);
      p.Pmb[(size_t)(n0+node)*64 + lane] = f2b(e/ss);
    }
  }
}

// ---------------- k2: per-batch anchor compression (source-grouped) ----------
// grid = 128 chunks x 4 sources; block accumulates [NT subtiles][16 r] in regs
__global__ __launch_bounds__(256) void k2(GP p){
  const int tid = threadIdx.x;
  const int chunk = blockIdx.x >> 2, src_id = blockIdx.x & 3;
  const int n0 = chunk * 512;
  const u16* src; int W, NT, fbase; bool isCK;
  if (src_id==0)      { src=p.Ks; W=256; NT=4; isCK=true;  fbase=0;   }
  else if (src_id==1) { src=p.Kv; W=192; NT=3; isCK=true;  fbase=256; }
  else if (src_id==2) { src=p.Vs; W=256; NT=4; isCK=false; fbase=0;   }
  else                { src=p.Vv; W=192; NT=3; isCK=false; fbase=256; }
  const int fl = tid&63, rg = tid>>6;
  __shared__ __align__(16) float Pl[1024];
  __shared__ __align__(16) u16 Fl[4096];
  __shared__ int Bl[16];
  float acc[4][16];
  #pragma unroll
  for (int t=0;t<4;t++)
    #pragma unroll
    for (int j=0;j<16;j++) acc[t][j]=0.f;
  int curb = p.bidx[n0];

  auto flush = [&](int b){
    if (isCK){
      #pragma unroll
      for (int t=0;t<4;t++) if (t<NT){
        int basei = (b*448 + fbase + t*64 + fl)*64 + rg*16;
        #pragma unroll
        for (int j=0;j<16;j++){ atomicAdd(&p.CK[basei+j], acc[t][j]); acc[t][j]=0.f; }
      }
    } else {
      #pragma unroll
      for (int t=0;t<4;t++) if (t<NT){
        int f = fbase + t*64 + fl;
        int rb = b*64 + rg*16;
        #pragma unroll
        for (int j=0;j<16;j++){ atomicAdd(&p.CV[(rb+j)*448 + f], acc[t][j]); acc[t][j]=0.f; }
      }
    }
  };

  for (int base=0; base<512; base+=16){
    __syncthreads();
    for (int idx=tid; idx<1024; idx+=256)
      Pl[idx] = b2f(p.Pmb[(size_t)(n0+base+(idx>>6))*64 + (idx&63)]);
    for (int nn=0; nn<16; nn++)
      if (tid < W) Fl[nn*W + tid] = src[(size_t)(n0+base+nn)*W + tid];
    if (tid < 16) Bl[tid] = p.bidx[n0+base+tid];
    __syncthreads();
    for (int nn=0; nn<16; nn++){
      int b = Bl[nn];
      if (b != curb){ flush(curb); curb = b; }
      const float* pr = &Pl[nn*64 + rg*16];
      float4 q0 = *reinterpret_cast<const float4*>(pr+0);
      float4 q1 = *reinterpret_cast<const float4*>(pr+4);
      float4 q2 = *reinterpret_cast<const float4*>(pr+8);
      float4 q3 = *reinterpret_cast<const float4*>(pr+12);
      #pragma unroll
      for (int t=0;t<4;t++) if (t<NT){
        float x = b2f(Fl[nn*W + t*64 + fl]);
        acc[t][0]+=q0.x*x;  acc[t][1]+=q0.y*x;  acc[t][2]+=q0.z*x;  acc[t][3]+=q0.w*x;
        acc[t][4]+=q1.x*x;  acc[t][5]+=q1.y*x;  acc[t][6]+=q1.z*x;  acc[t][7]+=q1.w*x;
        acc[t][8]+=q2.x*x;  acc[t][9]+=q2.y*x;  acc[t][10]+=q2.z*x; acc[t][11]+=q2.w*x;
        acc[t][12]+=q3.x*x; acc[t][13]+=q3.y*x; acc[t][14]+=q3.z*x; acc[t][15]+=q3.w*x;
      }
    }
  }
  flush(curb);
}

// ------------- k2b: pack CK (with SCALE) and CV into bf16 B-fragments --------
__global__ __launch_bounds__(256) void k2b(GP p){
  int idx = blockIdx.x*256 + threadIdx.x;
  if (idx < 229376){
    int b=idx/28672, r=idx%28672;
    int ks=r/2048, r2=r%2048, nt=r2/512, r3=r2%512, ln=r3/8, j=r3&7;
    int f=ks*32+((ln>>4)*8)+j, rr=nt*16+(ln&15);
    p.CKP[idx] = f2b(p.CK[((size_t)b*448+f)*64+rr] * 0.047245559f);
    return;
  }
  idx -= 229376;
  int b=idx/28672, r=idx%28672;
  int ks=r/14336, r2=r%14336, nt=r2/512, r3=r2%512, ln=r3/8, j=r3&7;
  int rr=ks*32+((ln>>4)*8)+j, f=nt*16+(ln&15);
  p.CVP[idx] = f2b(p.CV[((size_t)b*64+rr)*448+f]);
}

// =============== 16-node MFMA helpers (k3) ==================================
__device__ __forceinline__ void mfma_vh_vn(const u16* whPs, const u16* xvb, u16* vhb2,
                                           u16* xsb, int lane, int wave, int tid){
  fx4 a0={0,0,0,0}, a1={0,0,0,0}, a2={0,0,0,0};
  #pragma unroll
  for (int ks=0; ks<2; ks++){
    bs8 b = glb8(whPs + (ks*4+wave)*512 + lane*8);
    bs8 x0 = lds8(xvb + ( 0 + (lane&15))*XVB_P + ks*32 + ((lane>>4)*8));
    bs8 x1 = lds8(xvb + (16 + (lane&15))*XVB_P + ks*32 + ((lane>>4)*8));
    bs8 x2 = lds8(xvb + (32 + (lane&15))*XVB_P + ks*32 + ((lane>>4)*8));
    a0 = MFMA16(x0,b,a0); a1 = MFMA16(x1,b,a1); a2 = MFMA16(x2,b,a2);
  }
  int h = wave*16 + (lane&15);
  int mrow = (lane>>4)*4;
  #pragma unroll
  for (int r=0;r<4;r++){
    vhb2[( 0+mrow+r)*XVB_P + h] = f2b(a0[r]);
    vhb2[(16+mrow+r)*XVB_P + h] = f2b(a1[r]);
    vhb2[(32+mrow+r)*XVB_P + h] = f2b(a2[r]);
  }
  __syncthreads();
  for (int i=tid; i<1024; i+=256){
    int node=i>>6, hh=i&63;
    float a=b2f(vhb2[node*XVB_P+hh]);
    float b=b2f(vhb2[(16+node)*XVB_P+hh]);
    float c=b2f(vhb2[(32+node)*XVB_P+hh]);
    xsb[node*XSB_P + 256 + hh] = f2b(sqrtf(fmaxf(a*a+b*b+c*c, 1e-8f)));
  }
  __syncthreads();
}

template<int KS>
__device__ __forceinline__ void mfma_sgemm(const u16* wsPs, const float* bias,
                                           const u16* xsb, int lane, int wave, fx4 acc[4]){
  #pragma unroll
  for (int t=0;t<4;t++) acc[t] = (fx4){0.f,0.f,0.f,0.f};
  const u16* arow = xsb + (lane&15)*XSB_P + ((lane>>4)*8);
  #pragma unroll
  for (int ks=0; ks<KS; ks++){
    bs8 a = lds8(arow + ks*32);
    #pragma unroll
    for (int t=0;t<4;t++){
      bs8 b = glb8(wsPs + (ks*16 + wave*4 + t)*512 + lane*8);
      acc[t] = MFMA16(a,b,acc[t]);
    }
  }
  #pragma unroll
  for (int t=0;t<4;t++){
    float bv = bias[(wave*4+t)*16 + (lane&15)];
    acc[t][0]+=bv; acc[t][1]+=bv; acc[t][2]+=bv; acc[t][3]+=bv;
  }
}

__device__ __forceinline__ fx4 mfma_g64(const u16* bP, const u16* sgb, int lane, int wave){
  fx4 acc = {0.f,0.f,0.f,0.f};
  const u16* arow = sgb + (lane&15)*SGB_P + ((lane>>4)*8);
  #pragma unroll
  for (int ks=0; ks<8; ks++){
    bs8 a = lds8(arow + ks*32);
    bs8 b = glb8(bP + (ks*4 + wave)*512 + lane*8);
    acc = MFMA16(a,b,acc);
  }
  return acc;
}

__device__ __forceinline__ void mfma_wv(const u16* wvPs, const u16* vhb2,
                                        int lane, int wave, fx4 vo[3]){
  vo[0]=(fx4){0.f,0.f,0.f,0.f}; vo[1]=vo[0]; vo[2]=vo[0];
  #pragma unroll
  for (int ks=0; ks<2; ks++){
    bs8 b = glb8(wvPs + (ks*4+wave)*512 + lane*8);
    #pragma unroll
    for (int c=0;c<3;c++){
      bs8 a = lds8(vhb2 + (c*16 + (lane&15))*XVB_P + ks*32 + ((lane>>4)*8));
      vo[c] = MFMA16(a,b,vo[c]);
    }
  }
}

// ---------------- k3: MFMA attention + gating + output GVP -------------------
__global__ __launch_bounds__(256) void k3(GP p){
  __shared__ __align__(16) char smem[35072];
  u16* xq   = (u16*)smem;               // phase1: [16][XQ_P]
  u16* atb  = (u16*)(smem+15360);       // phase1: [16][AT_P]
  u16* xsb  = (u16*)(smem+17664);       // [16][XSB_P]
  u16* xvb  = (u16*)(smem+28160);       // [48][XVB_P]
  u16* vhb2 = (u16*)smem;               // phase2 (aliases xq)
  u16* sgb  = (u16*)(smem + 6912);      // phase2: [16][SGB_P]
  __shared__ float redm[4][16];
  __shared__ float reds[4][16];
  __shared__ int Bl[16];
  const int tid = threadIdx.x;
  const int n0 = blockIdx.x * 16;
  const int lane = tid & 63, wave = tid >> 6;

  for (int idx=tid; idx<7168; idx+=256){
    int node=idx/448, f=idx-node*448;
    float v = (f<256) ? p.Qs[(size_t)(n0+node)*256+f]
                      : p.Qv[(size_t)(n0+node)*192+(f-256)];
    xq[node*XQ_P+f] = f2b(v);
  }
  if (tid<16) Bl[tid] = p.bidx[n0+tid];
  __syncthreads();

  int bb = Bl[0];
  while (true){
    fx4 lac = {0.f,0.f,0.f,0.f};
    {
      const u16* ckb = p.CKP + (size_t)bb*28672;
      const u16* arow = xq + (lane&15)*XQ_P + ((lane>>4)*8);
      #pragma unroll
      for (int ks=0; ks<14; ks++){
        bs8 a = lds8(arow + ks*32);
        bs8 b = glb8(ckb + (ks*4+wave)*512 + lane*8);
        lac = MFMA16(a,b,lac);
      }
    }
    float loc[4];
    #pragma unroll
    for (int r=0;r<4;r++){
      float m = lac[r];
      #pragma unroll
      for (int o=1;o<16;o<<=1) m = fmaxf(m, __shfl_xor(m,o));
      loc[r]=m;
    }
    if ((lane&15)==0){
      #pragma unroll
      for (int r=0;r<4;r++) redm[wave][((lane>>4)*4)+r]=loc[r];
    }
    __syncthreads();
    float e4[4];
    #pragma unroll
    for (int r=0;r<4;r++){
      int node=((lane>>4)*4)+r;
      float gm = fmaxf(fmaxf(redm[0][node],redm[1][node]),
                       fmaxf(redm[2][node],redm[3][node]));
      float e = __expf(lac[r]-gm);
      e4[r]=e;
      float s=e;
      #pragma unroll
      for (int o=1;o<16;o<<=1) s += __shfl_xor(s,o);
      loc[r]=s;
    }
    if ((lane&15)==0){
      #pragma unroll
      for (int r=0;r<4;r++) reds[wave][((lane>>4)*4)+r]=loc[r];
    }
    __syncthreads();
    #pragma unroll
    for (int r=0;r<4;r++){
      int node=((lane>>4)*4)+r;
      float tot = reds[0][node]+reds[1][node]+reds[2][node]+reds[3][node];
      atb[node*AT_P + wave*16 + (lane&15)] = f2b(e4[r]/tot);
    }
    __syncthreads();
    {
      const u16* cvb = p.CVP + (size_t)bb*28672;
      const u16* prow = atb + (lane&15)*AT_P + ((lane>>4)*8);
      bs8 a0 = lds8(prow);
      bs8 a1 = lds8(prow + 32);
      #pragma unroll
      for (int t=0;t<7;t++){
        int nt = wave*7 + t;
        fx4 pv = {0.f,0.f,0.f,0.f};
        pv = MFMA16(a0, glb8(cvb + nt*512 + lane*8), pv);
        pv = MFMA16(a1, glb8(cvb + (28+nt)*512 + lane*8), pv);
        int f = nt*16 + (lane&15);
        #pragma unroll
        for (int r=0;r<4;r++){
          int node=((lane>>4)*4)+r;
          if (Bl[node]!=bb) continue;
          int n = n0+node;
          if (f < 256){
            float gs = b2f(p.Gs[(size_t)n*256+f]);
            xsb[node*XSB_P+f] = f2b(pv[r]*gs);
          } else {
            int fm=f-256, c=fm>>6, d=fm&63;
            xvb[(c*16+node)*XVB_P+d] = f2b(pv[r]*p.Gv[n]);
          }
        }
      }
    }
    int nxt = 0x7fffffff;
    #pragma unroll
    for (int i=0;i<16;i++){ int v=Bl[i]; if (v>bb && v<nxt) nxt=v; }
    if (nxt==0x7fffffff) break;
    bb = nxt;
    __syncthreads();
  }
  __syncthreads();

  mfma_vh_vn(p.whP + 4*4096, xvb, vhb2, xsb, lane, wave, tid);
  fx4 acc[4];
  mfma_sgemm<10>(p.wsP + (size_t)4*81920, p.wsb_f + 4*256, xsb, lane, wave, acc);
  #pragma unroll
  for (int t=0;t<4;t++){
    int ncol=(wave*4+t)*16+(lane&15);
    #pragma unroll
    for (int r=0;r<4;r++){
      int node=((lane>>4)*4)+r;
      float v=acc[t][r];
      p.Qs[(size_t)(n0+node)*256+ncol]=siluf(v);
      sgb[node*SGB_P+ncol]=f2b(sigm(v));
    }
  }
  __syncthreads();
  fx4 g = mfma_g64(p.wsvP + 3*16384, sgb, lane, wave);
  fx4 vo[3];
  mfma_wv(p.wvP + 3*4096, vhb2, lane, wave, vo);
  int dout = wave*16+(lane&15);
  #pragma unroll
  for (int r=0;r<4;r++){
    int node=((lane>>4)*4)+r;
    float gg = sigm(g[r] + p.wsvb_f[3*64+dout]);
    #pragma unroll
    for (int c=0;c<3;c++)
      p.Qv[(size_t)(n0+node)*192 + dout*3 + c] = vo[c][r]*gg;   // [N,DV,3]
  }
}

// ---------------- host ------------------------------------------------------
extern "C" void kernel_launch(void* const* d_in, const int* in_sizes, int n_in,
                              void* d_out, int out_size, void* d_ws, size_t ws_size,
                              hipStream_t stream){
  (void)in_sizes; (void)n_in; (void)out_size; (void)ws_size;
  GP p;
  p.x_s  = (const float*)d_in[0];
  p.x_v  = (const float*)d_in[1];
  p.bidx = (const int*)d_in[2];
  // set order: 0=q 1=k 2=v 3=g 4=o  (wv/wsv: 0=q 1=k 2=v 3=o)
  const int whI[5]  = {3, 9, 15, 33, 21};
  const int wswI[5] = {4, 10, 16, 34, 22};
  const int wsbI[5] = {5, 11, 17, 35, 23};
  const int wvI[4]  = {6, 12, 18, 24};
  const int wsvwI[4]= {7, 13, 19, 25};
  const int wsvbI[4]= {8, 14, 20, 26};
  for (int s=0;s<5;s++){
    p.wh[s]   = (const float*)d_in[whI[s]];
    p.ws_w[s] = (const float*)d_in[wswI[s]];
    p.ws_b[s] = (const float*)d_in[wsbI[s]];
  }
  for (int s=0;s<4;s++){
    p.wv[s]    = (const float*)d_in[wvI[s]];
    p.wsv_w[s] = (const float*)d_in[wsvwI[s]];
    p.wsv_b[s] = (const float*)d_in[wsvbI[s]];
  }
  p.w1    = (const float*)d_in[27];
  p.b1    = (const float*)d_in[28];
  p.lng   = (const float*)d_in[29];
  p.lnb   = (const float*)d_in[30];
  p.w2    = (const float*)d_in[31];
  p.b2    = (const float*)d_in[32];
  p.gbias = (const float*)d_in[36];

  char* w = (char*)d_ws;
  auto alloc = [&](size_t bytes)->char*{
    char* r = w; w += (bytes + 255) & ~(size_t)255; return r;
  };
  p.wsP   = (u16*)alloc(409600u*2);
  p.whP   = (u16*)alloc(20480u*2);
  p.wvP   = (u16*)alloc(16384u*2);
  p.wsvP  = (u16*)alloc(65536u*2);
  p.w1P   = (u16*)alloc(65536u*2);
  p.w2P   = (u16*)alloc(16384u*2);
  p.wsb_f  = (float*)alloc(1280u*4);
  p.wsvb_f = (float*)alloc(256u*4);
  p.b1_f   = (float*)alloc(256u*4);
  p.b2_f   = (float*)alloc(64u*4);
  p.lng_f  = (float*)alloc(256u*4);
  p.lnb_f  = (float*)alloc(256u*4);
  p.gb_f   = (float*)alloc(256u*4);
  p.Ks = (u16*)alloc((size_t)65536*256*2);
  p.Vs = (u16*)alloc((size_t)65536*256*2);
  p.Kv = (u16*)alloc((size_t)65536*192*2);
  p.Vv = (u16*)alloc((size_t)65536*192*2);
  p.Gs = (u16*)alloc((size_t)65536*256*2);
  p.Pmb = (u16*)alloc((size_t)65536*64*2);
  p.Gv = (float*)alloc((size_t)65536*4);
  p.CK = (float*)alloc((size_t)8*448*64*4);
  p.CV = (float*)alloc((size_t)8*448*64*4);
  p.CKP = (u16*)alloc((size_t)8*448*64*2);
  p.CVP = (u16*)alloc((size_t)8*448*64*2);
  p.Qs = (float*)d_out;
  p.Qv = (float*)d_out + (size_t)65536*256;

  hipMemsetAsync(p.CK, 0, (size_t)8*448*64*4, stream);
  hipMemsetAsync(p.CV, 0, (size_t)8*448*64*4, stream);
  kprep<<<2331, 256, 0, stream>>>(p);
  k1<<<2048, 256, 0, stream>>>(p);
  k2<<<512, 256, 0, stream>>>(p);
  k2b<<<1792, 256, 0, stream>>>(p);
  k3<<<4096, 256, 0, stream>>>(p);
}